// Round 8
// baseline (372.760 us; speedup 1.0000x reference)
//
#include <hip/hip_runtime.h>
#include <hip/hip_bf16.h>

// GraphSAGE fwd on MI355X, v7.
// v6 -> v7: (1) agg2+FC fusion REVERTED (measured -20us loss: barrier-coupled
// 8-wave blocks tank gather occupancy). agg_epi used for both layers; v4's
// fc_kernel restored. (2) agg gather deepened: neighbor lists padded to x16,
// 4 uint4 gathers in flight per wave per iter -> 2x outstanding L2-misses
// (the 2.3 TB/s miss path was concurrency-starved, not saturated).
// Pipeline: [memsets] prep∪bucket | csr∪gemm1 | agg1 | gemm2 | agg2 | fc.

#define N_NODES 100000
#define N_EDGES 1600000
#define NBUCK   196      // ceil(N/512)
#define BCAP    12288    // raw slots per bucket (mean 8163, +45 sigma)
#define PB_CAP  14336    // padded csr region per bucket (E[sum]~12700 @ pad16)
#define CHUNK   4096     // edges per bucket block
#define PREP_BLKS 432    // 432*256 = 110592 prep elements exactly
#define GEMM1_BLKS 782   // ceil(N/128)

typedef unsigned short u16;
typedef unsigned int u32;
typedef __bf16 bf16x8 __attribute__((ext_vector_type(8)));
typedef float  f32x4  __attribute__((ext_vector_type(4)));

__device__ __forceinline__ u16 f2b(float f) {
  unsigned x = __builtin_bit_cast(unsigned, f);
  unsigned r = x + 0x7fffu + ((x >> 16) & 1u);
  return (u16)(r >> 16);
}
__device__ __forceinline__ bf16x8 ldfrag(const u16* p) {
  uint4 u = *reinterpret_cast<const uint4*>(p);
  return __builtin_bit_cast(bf16x8, u);
}
__device__ __forceinline__ void unpack8(uint4 u, float* f) {
  f[0] = __builtin_bit_cast(float, u.x << 16);
  f[1] = __builtin_bit_cast(float, u.x & 0xffff0000u);
  f[2] = __builtin_bit_cast(float, u.y << 16);
  f[3] = __builtin_bit_cast(float, u.y & 0xffff0000u);
  f[4] = __builtin_bit_cast(float, u.z << 16);
  f[5] = __builtin_bit_cast(float, u.z & 0xffff0000u);
  f[6] = __builtin_bit_cast(float, u.w << 16);
  f[7] = __builtin_bit_cast(float, u.w & 0xffff0000u);
}
__device__ __forceinline__ uint4 pack8(const float* f) {
  uint4 u;
  u.x = (u32)f2b(f[0]) | ((u32)f2b(f[1]) << 16);
  u.y = (u32)f2b(f[2]) | ((u32)f2b(f[3]) << 16);
  u.z = (u32)f2b(f[4]) | ((u32)f2b(f[5]) << 16);
  u.w = (u32)f2b(f[6]) | ((u32)f2b(f[7]) << 16);
  return u;
}

__device__ __forceinline__ int wave_incl_scan(int x, int lane) {
#pragma unroll
  for (int d = 1; d < 64; d <<= 1) {
    int n = __shfl_up(x, d, 64);
    if (lane >= d) x += n;
  }
  return x;
}

// ================= dispatch 1: prep ∪ bucket (256 thr) =================
__device__ void prep_body(int bid, const float* __restrict__ w1s,
                          const float* __restrict__ w1n,
                          const float* __restrict__ w2s,
                          const float* __restrict__ w2n,
                          const float* __restrict__ wfc, u16* __restrict__ WT1,
                          u16* __restrict__ WT2, u16* __restrict__ WFCT) {
  int i = bid * 256 + threadIdx.x;
  if (i < 32768) {                       // WT1: [256 cols][128 k]
    int c = i >> 7, k = i & 127;
    float v = (c < 128) ? w1s[k * 128 + c] : w1n[k * 128 + (c - 128)];
    WT1[c * 128 + k] = f2b(v);
  } else if (i < 32768 + 65536) {        // WT2: [256 cols][256 k]
    int j = i - 32768;
    int c = j >> 8, k = j & 255;
    float v = (c < 128) ? w2s[k * 128 + c] : w2n[k * 128 + (c - 128)];
    WT2[c * 256 + k] = f2b(v);
  } else {                               // WFCT: [48 cols][256 k], 40..47 zero
    int j = i - 98304;
    int c = j >> 8, k = j & 255;
    float v = (c < 40) ? wfc[k * 40 + c] : 0.f;
    WFCT[c * 256 + k] = f2b(v);
  }
}

__global__ __launch_bounds__(256) void prep_bucket_kernel(
    const float* __restrict__ w1s, const float* __restrict__ w1n,
    const float* __restrict__ w2s, const float* __restrict__ w2n,
    const float* __restrict__ wfc, u16* __restrict__ WT1,
    u16* __restrict__ WT2, u16* __restrict__ WFCT,
    const int* __restrict__ src, const int* __restrict__ dst,
    int* __restrict__ cntg, u32* __restrict__ pairBuf) {
  if (blockIdx.x < PREP_BLKS) {
    prep_body(blockIdx.x, w1s, w1n, w2s, w2n, wfc, WT1, WT2, WFCT);
    return;
  }
  // ---- bucket body ----
  __shared__ unsigned hist[NBUCK];
  __shared__ unsigned gbase[NBUCK];
  __shared__ int sws[4];
  __shared__ u32 stage[CHUNK];     // 16 KB
  __shared__ int tgt[CHUNK];       // 16 KB
  const int tid = threadIdx.x, lane = tid & 63, wid = tid >> 6;
  const int e0 = (blockIdx.x - PREP_BLKS) * CHUNK;

  for (int i = tid; i < NBUCK; i += 256) hist[i] = 0u;
  __syncthreads();

  u32 myW[16];
  int myR[16], myB[16];
#pragma unroll
  for (int k = 0; k < 16; ++k) {
    int e = e0 + k * 256 + tid;
    if (e < N_EDGES) {
      unsigned d = (unsigned)dst[e];
      myW[k] = ((d & 511u) << 17) | (unsigned)src[e];
      myB[k] = (int)(d >> 9);
      myR[k] = (int)atomicAdd(&hist[myB[k]], 1u);
    } else {
      myB[k] = -1;
    }
  }
  __syncthreads();

  int cnt = (tid < NBUCK) ? (int)hist[tid] : 0;
  int inc = wave_incl_scan(cnt, lane);
  if (lane == 63) sws[wid] = inc;
  __syncthreads();
  if (wid == 0) {
    int s = (lane < 4) ? sws[lane] : 0;
    s = wave_incl_scan(s, lane);
    if (lane < 4) sws[lane] = s;
  }
  __syncthreads();
  int excl = (wid ? sws[wid - 1] : 0) + inc - cnt;
  int gofs = 0;
  if (tid < NBUCK && cnt > 0) gofs = tid * BCAP + atomicAdd(&cntg[tid], cnt);
  __syncthreads();
  if (tid < NBUCK) {
    hist[tid] = (unsigned)excl;
    gbase[tid] = (unsigned)gofs;
  }
  __syncthreads();

#pragma unroll
  for (int k = 0; k < 16; ++k) {
    if (myB[k] >= 0) {
      int slot = (int)hist[myB[k]] + myR[k];
      stage[slot] = myW[k];
      tgt[slot] = (int)gbase[myB[k]] + myR[k];
    }
  }
  __syncthreads();
  int nvalid = N_EDGES - e0;
  if (nvalid > CHUNK) nvalid = CHUNK;
  for (int i = tid; i < nvalid; i += 256) pairBuf[tgt[i]] = stage[i];
}

// ================= dispatch 2: csr_build ∪ gemm1 (512 thr, 64KB dyn LDS) =================
__device__ void csr_body(char* smem, int b, const u32* __restrict__ pairBuf,
                         const int* __restrict__ cntg, int* __restrict__ rowptr,
                         int* __restrict__ degA, int* __restrict__ csr) {
  int* lcnt = (int*)smem;            // 512
  int* lofs = lcnt + 512;            // 512
  int* sws = lofs + 512;             // 8
  int* cstage = sws + 8;             // PB_CAP
  const int tid = threadIdx.x;
  const int lane = tid & 63, wid = tid >> 6;
  int nb = cntg[b];
  if (nb > BCAP) nb = BCAP;
  const u32* pp = pairBuf + (size_t)b * BCAP;

  lcnt[tid] = 0;
  __syncthreads();
  for (int i = tid; i < nb; i += 512) atomicAdd(&lcnt[(pp[i] >> 17) & 511], 1);
  __syncthreads();
  int dg = lcnt[tid];
  int pd = (dg + 15) & ~15;          // pad to x16 for 4-deep gather
  int inc = wave_incl_scan(pd, lane);
  if (lane == 63) sws[wid] = inc;
  __syncthreads();
  if (wid == 0) {
    int s = (lane < 8) ? sws[lane] : 0;
    s = wave_incl_scan(s, lane);
    if (lane < 8) sws[lane] = s;
  }
  __syncthreads();
  int excl = (wid ? sws[wid - 1] : 0) + inc - pd;
  int ptot = sws[7];
  int node = b * 512 + tid;
  if (node < N_NODES) {
    rowptr[node] = b * PB_CAP + excl;
    degA[node] = dg;
  }
  lofs[tid] = excl;
  __syncthreads();
  for (int i = tid; i < nb; i += 512) {
    u32 pr = pp[i];
    int pos = atomicAdd(&lofs[(pr >> 17) & 511], 1);
    if (pos < PB_CAP) cstage[pos] = (int)(pr & 0x1FFFFu);
  }
  __syncthreads();
  for (int k = excl + dg; k < excl + pd; ++k)
    if (k < PB_CAP) cstage[k] = N_NODES;  // sentinel pads (zeroed row)
  __syncthreads();
  if (ptot > PB_CAP) ptot = PB_CAP;
  for (int i = tid; i < ptot; i += 512) csr[b * PB_CAP + i] = cstage[i];
}

__device__ void gemm1_body(char* smem, int bid, const float* __restrict__ A,
                           const u16* __restrict__ WT, u16* __restrict__ Cs,
                           u16* __restrict__ Cn) {
  char* lbc = smem;   // 64 KB: [256 cols][128 k], swizzled RB=256
  const int tid = threadIdx.x;
  for (int i = tid; i < 4096; i += 512) {
    uint4 v = *reinterpret_cast<const uint4*>(WT + i * 8);
    int byte = i * 16;
    int swz = byte ^ (((byte >> 8) & 7) << 4);
    *reinterpret_cast<uint4*>(lbc + swz) = v;
  }

  const int w = tid >> 6, lane = tid & 63;
  const int lrow = lane & 15, lk = lane >> 4;
  const int xr = (lrow & 7) << 4;
  const int rbase = bid * 128 + w * 16;

  bf16x8 af[4];
  {
    int r = rbase + lrow;
    if (r >= N_NODES) r = N_NODES - 1;
    const float* ap = A + (size_t)r * 128 + lk * 8;
#pragma unroll
    for (int ks = 0; ks < 4; ++ks) {
      float4 f0 = *reinterpret_cast<const float4*>(ap + ks * 32);
      float4 f1 = *reinterpret_cast<const float4*>(ap + ks * 32 + 4);
      float f[8] = {f0.x, f0.y, f0.z, f0.w, f1.x, f1.y, f1.z, f1.w};
      af[ks] = __builtin_bit_cast(bf16x8, pack8(f));
    }
  }
  __syncthreads();

  f32x4 acc[16];
#pragma unroll
  for (int ct = 0; ct < 16; ++ct) acc[ct] = f32x4{0.f, 0.f, 0.f, 0.f};
#pragma unroll
  for (int ks = 0; ks < 4; ++ks) {
#pragma unroll
    for (int ct = 0; ct < 16; ++ct) {
      int byte = (ct * 16 + lrow) * 256 + ks * 64 + lk * 16;
      bf16x8 b = __builtin_bit_cast(
          bf16x8, *reinterpret_cast<const uint4*>(lbc + (byte ^ xr)));
      acc[ct] = __builtin_amdgcn_mfma_f32_16x16x32_bf16(af[ks], b, acc[ct], 0, 0, 0);
    }
  }
#pragma unroll
  for (int j = 0; j < 4; ++j) {
    int r = rbase + lk * 4 + j;
    if (r < N_NODES) {
      u16* cs = Cs + (size_t)r * 128 + lrow;
      u16* cn = Cn + (size_t)r * 128 + lrow;
#pragma unroll
      for (int ct = 0; ct < 8; ++ct) cs[ct * 16] = f2b(acc[ct][j]);
#pragma unroll
      for (int ct = 0; ct < 8; ++ct) cn[ct * 16] = f2b(acc[8 + ct][j]);
    }
  }
}

__global__ __launch_bounds__(512) void csr_gemm1_kernel(
    const u32* __restrict__ pairBuf, const int* __restrict__ cntg,
    int* __restrict__ rowptr, int* __restrict__ degA, int* __restrict__ csr,
    const float* __restrict__ A, const u16* __restrict__ WT,
    u16* __restrict__ Cs, u16* __restrict__ Cn) {
  extern __shared__ char smem[];
  if (blockIdx.x < NBUCK) {
    csr_body(smem, blockIdx.x, pairBuf, cntg, rowptr, degA, csr);
  } else {
    gemm1_body(smem, blockIdx.x - NBUCK, A, WT, Cs, Cn);
  }
}

// ================= aggregation helper: 4 gathers in flight =================
__device__ __forceinline__ void agg_node(
    const u16* __restrict__ Xs, const u16* __restrict__ Xn,
    const int* __restrict__ rowptr, const int* __restrict__ degA,
    const int* __restrict__ csr, const float* __restrict__ bs,
    const float* __restrict__ bn, int node, int g, int lc,
    float* sf, float* nf) {
  int beg = rowptr[node], dg = degA[node];
  int cnt = (dg + 15) & ~15;
  float acc[8] = {0.f, 0.f, 0.f, 0.f, 0.f, 0.f, 0.f, 0.f};
  const u16* colbase = Xn + lc * 8;
  const int* cp = csr + beg;
  for (int j = 0; j < cnt; j += 16) {
    int s0 = cp[j + g];
    int s1 = cp[j + 4 + g];
    int s2 = cp[j + 8 + g];
    int s3 = cp[j + 12 + g];
    uint4 u0 = *reinterpret_cast<const uint4*>(colbase + (size_t)s0 * 128);
    uint4 u1 = *reinterpret_cast<const uint4*>(colbase + (size_t)s1 * 128);
    uint4 u2 = *reinterpret_cast<const uint4*>(colbase + (size_t)s2 * 128);
    uint4 u3 = *reinterpret_cast<const uint4*>(colbase + (size_t)s3 * 128);
    float f0[8], f1[8], f2[8], f3[8];
    unpack8(u0, f0);
    unpack8(u1, f1);
    unpack8(u2, f2);
    unpack8(u3, f3);
#pragma unroll
    for (int i = 0; i < 8; ++i) acc[i] += (f0[i] + f1[i]) + (f2[i] + f3[i]);
  }
#pragma unroll
  for (int i = 0; i < 8; ++i) {
    acc[i] += __shfl_xor(acc[i], 32, 64);
    acc[i] += __shfl_xor(acc[i], 16, 64);
  }
  float inv = 1.f / (float)(dg > 0 ? dg : 1);
  uint4 sv4 = *reinterpret_cast<const uint4*>(Xs + (size_t)node * 128 + lc * 8);
  unpack8(sv4, sf);
  float4 b0 = *reinterpret_cast<const float4*>(bs + lc * 8);
  float4 b1 = *reinterpret_cast<const float4*>(bs + lc * 8 + 4);
  float4 c0 = *reinterpret_cast<const float4*>(bn + lc * 8);
  float4 c1 = *reinterpret_cast<const float4*>(bn + lc * 8 + 4);
  float bsv[8] = {b0.x, b0.y, b0.z, b0.w, b1.x, b1.y, b1.z, b1.w};
  float bnv[8] = {c0.x, c0.y, c0.z, c0.w, c1.x, c1.y, c1.z, c1.w};
  float ss = 0.f;
#pragma unroll
  for (int i = 0; i < 8; ++i) {
    sf[i] = fmaxf(sf[i] + bsv[i], 0.f);
    nf[i] = fmaxf(acc[i] * inv + bnv[i], 0.f);
    ss += sf[i] * sf[i] + nf[i] * nf[i];
  }
  ss += __shfl_xor(ss, 1, 64);
  ss += __shfl_xor(ss, 2, 64);
  ss += __shfl_xor(ss, 4, 64);
  ss += __shfl_xor(ss, 8, 64);
  float sc = 1.f / fmaxf(sqrtf(ss), 1e-12f);
#pragma unroll
  for (int i = 0; i < 8; ++i) {
    sf[i] *= sc;
    nf[i] *= sc;
  }
}

// ================= agg (persistent grid-stride), writes H [N,256] =================
__global__ __launch_bounds__(256) void agg_epi_kernel(
    const u16* __restrict__ Xs, const u16* __restrict__ Xn,
    const int* __restrict__ rowptr, const int* __restrict__ degA,
    const int* __restrict__ csr, const float* __restrict__ bs,
    const float* __restrict__ bn, u16* __restrict__ H) {
  const int lane = threadIdx.x & 63;
  const int g = lane >> 4, lc = lane & 15;
  const int wave0 = blockIdx.x * 4 + (threadIdx.x >> 6);
  const int stride = gridDim.x * 4;
  for (int node = wave0; node < N_NODES; node += stride) {
    float sf[8], nf[8];
    agg_node(Xs, Xn, rowptr, degA, csr, bs, bn, node, g, lc, sf, nf);
    if (g == 0) {
      *reinterpret_cast<uint4*>(H + (size_t)node * 256 + lc * 8) = pack8(sf);
    } else if (g == 1) {
      *reinterpret_cast<uint4*>(H + (size_t)node * 256 + 128 + lc * 8) = pack8(nf);
    }
  }
}

// ================= gemm2 =================
__global__ __launch_bounds__(512) void gemm2_kernel(
    const u16* __restrict__ A, const u16* __restrict__ WT,
    u16* __restrict__ Cs, u16* __restrict__ Cn) {
  __shared__ u16 lb[128 * 256];   // 64 KB: [128 cols][256 k], swizzled RB=512
  char* lbc = reinterpret_cast<char*>(lb);
  const int tid = threadIdx.x;
  const int w = tid >> 6, lane = tid & 63;
  const int lrow = lane & 15, lk = lane >> 4;
  const int xr = (lrow & 7) << 4;
  const int rbase = blockIdx.x * 128 + w * 16;

  bf16x8 af[8];
  {
    int r = rbase + lrow;
    if (r >= N_NODES) r = N_NODES - 1;
    const u16* ap = A + (size_t)r * 256 + lk * 8;
#pragma unroll
    for (int ks = 0; ks < 8; ++ks) af[ks] = ldfrag(ap + ks * 32);
  }

#pragma unroll
  for (int half = 0; half < 2; ++half) {
    const u16* Wsrc = WT + (size_t)half * 128 * 256;
    for (int i = tid; i < 4096; i += 512) {
      uint4 v = *reinterpret_cast<const uint4*>(Wsrc + i * 8);
      int byte = i * 16;
      int swz = byte ^ (((byte >> 9) & 7) << 4);
      *reinterpret_cast<uint4*>(lbc + swz) = v;
    }
    __syncthreads();

    f32x4 acc[8];
#pragma unroll
    for (int ct = 0; ct < 8; ++ct) acc[ct] = f32x4{0.f, 0.f, 0.f, 0.f};
#pragma unroll
    for (int ks = 0; ks < 8; ++ks) {
#pragma unroll
      for (int ct = 0; ct < 8; ++ct) {
        int byte = (ct * 16 + lrow) * 512 + ks * 64 + lk * 16;
        bf16x8 b = __builtin_bit_cast(
            bf16x8, *reinterpret_cast<const uint4*>(lbc + (byte ^ xr)));
        acc[ct] = __builtin_amdgcn_mfma_f32_16x16x32_bf16(af[ks], b, acc[ct], 0, 0, 0);
      }
    }
    u16* __restrict__ Cout = half ? Cn : Cs;
#pragma unroll
    for (int j = 0; j < 4; ++j) {
      int r = rbase + lk * 4 + j;
      if (r < N_NODES) {
        u16* cp = Cout + (size_t)r * 128 + lrow;
#pragma unroll
        for (int ct = 0; ct < 8; ++ct) cp[ct * 16] = f2b(acc[ct][j]);
      }
    }
    __syncthreads();
  }
}

// ================= FC head: out[N,40] = h2 @ wfc + bfc =================
__global__ __launch_bounds__(256) void fc_kernel(const u16* __restrict__ H2,
                                                 const u16* __restrict__ WFCT,
                                                 const float* __restrict__ bfc,
                                                 float* __restrict__ Out) {
  __shared__ u16 lb[48 * 256];   // 24 KB, swizzled RB=512
  char* lbc = reinterpret_cast<char*>(lb);
  const int tid = threadIdx.x;
#pragma unroll
  for (int i = tid; i < 48 * 256 / 8; i += 256) {
    uint4 v = *reinterpret_cast<const uint4*>(WFCT + i * 8);
    int byte = i * 16;
    int swz = byte ^ (((byte >> 9) & 7) << 4);
    *reinterpret_cast<uint4*>(lbc + swz) = v;
  }
  __syncthreads();
  const int w = tid >> 6, lane = tid & 63;
  const int lrow = lane & 15, lk = lane >> 4;
  const int xr = (lrow & 7) << 4;
  const int rbase = blockIdx.x * 64 + w * 16;

  bf16x8 af[8];
  {
    int r = rbase + lrow;
    if (r >= N_NODES) r = N_NODES - 1;
    const u16* ap = H2 + (size_t)r * 256 + lk * 8;
#pragma unroll
    for (int ks = 0; ks < 8; ++ks) af[ks] = ldfrag(ap + ks * 32);
  }
  f32x4 acc[3];
#pragma unroll
  for (int ct = 0; ct < 3; ++ct) acc[ct] = f32x4{0.f, 0.f, 0.f, 0.f};
#pragma unroll
  for (int ks = 0; ks < 8; ++ks) {
#pragma unroll
    for (int ct = 0; ct < 3; ++ct) {
      int byte = (ct * 16 + lrow) * 512 + ks * 64 + lk * 16;
      bf16x8 b = __builtin_bit_cast(
          bf16x8, *reinterpret_cast<const uint4*>(lbc + (byte ^ xr)));
      acc[ct] = __builtin_amdgcn_mfma_f32_16x16x32_bf16(af[ks], b, acc[ct], 0, 0, 0);
    }
  }
#pragma unroll
  for (int j = 0; j < 4; ++j) {
    int r = rbase + lk * 4 + j;
    if (r < N_NODES) {
#pragma unroll
      for (int ct = 0; ct < 3; ++ct) {
        int col = ct * 16 + lrow;
        if (col < 40) Out[(size_t)r * 40 + col] = acc[ct][j] + bfc[col];
      }
    }
  }
}

// ================= launch =================
extern "C" void kernel_launch(void* const* d_in, const int* in_sizes, int n_in,
                              void* d_out, int out_size, void* d_ws, size_t ws_size,
                              hipStream_t stream) {
  const float* x = (const float*)d_in[0];
  const int* src = (const int*)d_in[1];
  const int* dst = (const int*)d_in[2];
  const float* w1s = (const float*)d_in[3];
  const float* b1s = (const float*)d_in[4];
  const float* w1n = (const float*)d_in[5];
  const float* b1n = (const float*)d_in[6];
  const float* w2s = (const float*)d_in[7];
  const float* b2s = (const float*)d_in[8];
  const float* w2n = (const float*)d_in[9];
  const float* b2n = (const float*)d_in[10];
  const float* wfc = (const float*)d_in[11];
  const float* bfc = (const float*)d_in[12];
  float* out = (float*)d_out;

  char* p = (char*)d_ws;
  auto alloc = [&](size_t bytes) {
    char* r = p;
    p += (bytes + 255) & ~(size_t)255;
    return r;
  };
  u16* XWs = (u16*)alloc((size_t)N_NODES * 128 * 2);        // 25.6 MB
  u16* XWn = (u16*)alloc(((size_t)N_NODES + 1) * 128 * 2);  // 25.6 MB (+sentinel)
  u16* h1 = (u16*)alloc((size_t)N_NODES * 256 * 2);         // 51.2 MB (h2 aliases)
  u16* WT1 = (u16*)alloc(32768 * 2);
  u16* WT2 = (u16*)alloc(65536 * 2);
  u16* WFCT = (u16*)alloc(12288 * 2);
  u32* pairBuf = (u32*)alloc((size_t)NBUCK * BCAP * 4);     // 9.6 MB
  int* cntg = (int*)alloc(NBUCK * 4);
  int* rowptr = (int*)alloc((size_t)N_NODES * 4);
  int* degA = (int*)alloc((size_t)N_NODES * 4);
  int* csr = (int*)alloc((size_t)NBUCK * PB_CAP * 4);       // 11.2 MB
  u16* h2 = h1;  // gemm2 finishes reading h1 before agg2 writes h2

  hipMemsetAsync(cntg, 0, NBUCK * 4, stream);
  hipMemsetAsync(XWn + (size_t)N_NODES * 128, 0, 256, stream);

  prep_bucket_kernel<<<PREP_BLKS + 391, 256, 0, stream>>>(
      w1s, w1n, w2s, w2n, wfc, WT1, WT2, WFCT, src, dst, cntg, pairBuf);
  csr_gemm1_kernel<<<NBUCK + GEMM1_BLKS, 512, 65536, stream>>>(
      pairBuf, cntg, rowptr, degA, csr, x, WT1, XWs, XWn);
  agg_epi_kernel<<<2048, 256, 0, stream>>>(XWs, XWn, rowptr, degA, csr, b1s, b1n, h1);
  gemm2_kernel<<<GEMM1_BLKS, 512, 0, stream>>>(h1, WT2, XWs, XWn);
  agg_epi_kernel<<<2048, 256, 0, stream>>>(XWs, XWn, rowptr, degA, csr, b2s, b2n, h2);
  fc_kernel<<<1563, 256, 0, stream>>>(h2, WFCT, bfc, out);
}

// Round 9
// 330.329 us; speedup vs baseline: 1.1285x; 1.1285x over previous
//
#include <hip/hip_runtime.h>
#include <hip/hip_bf16.h>

// GraphSAGE fwd on MI355X, v8.
// v7 -> v8: (1) fp8-e4m3 gather tables: gemm1/gemm2 write the neighbor-branch
// output XWn as fp8 (HW cvt_pk_fp8_f32 RNE); agg decodes with cvt_pk_f32_fp8.
// Halves the gather's miss bytes (the measured limiter) and shrinks the table
// to 12.8MB (< 32MB aggregate L2). (2) v7's regressions reverted: pad-8 /
// 2-deep gather, 25000-block agg grid (72% occupancy config).
// Pipeline: [memsets] prep∪bucket | csr∪gemm1 | agg1 | gemm2 | agg2 | fc.

#define N_NODES 100000
#define N_EDGES 1600000
#define NBUCK   196      // ceil(N/512)
#define BCAP    12288    // raw slots per bucket (mean 8163, +45 sigma)
#define PB_CAP  14336    // padded csr region per bucket (pad8: E[sum]~10000)
#define CHUNK   4096     // edges per bucket block
#define PREP_BLKS 432    // 432*256 = 110592 prep elements exactly
#define GEMM1_BLKS 782   // ceil(N/128)

typedef unsigned short u16;
typedef unsigned char u8;
typedef unsigned int u32;
typedef __bf16 bf16x8 __attribute__((ext_vector_type(8)));
typedef float  f32x4  __attribute__((ext_vector_type(4)));
typedef float  f32x2  __attribute__((ext_vector_type(2)));

__device__ __forceinline__ u16 f2b(float f) {
  unsigned x = __builtin_bit_cast(unsigned, f);
  unsigned r = x + 0x7fffu + ((x >> 16) & 1u);
  return (u16)(r >> 16);
}
__device__ __forceinline__ u8 f2fp8(float v) {
  int p = __builtin_amdgcn_cvt_pk_fp8_f32(v, v, 0, false);
  return (u8)(p & 0xff);
}
__device__ __forceinline__ bf16x8 ldfrag(const u16* p) {
  uint4 u = *reinterpret_cast<const uint4*>(p);
  return __builtin_bit_cast(bf16x8, u);
}
__device__ __forceinline__ void unpack8(uint4 u, float* f) {
  f[0] = __builtin_bit_cast(float, u.x << 16);
  f[1] = __builtin_bit_cast(float, u.x & 0xffff0000u);
  f[2] = __builtin_bit_cast(float, u.y << 16);
  f[3] = __builtin_bit_cast(float, u.y & 0xffff0000u);
  f[4] = __builtin_bit_cast(float, u.z << 16);
  f[5] = __builtin_bit_cast(float, u.z & 0xffff0000u);
  f[6] = __builtin_bit_cast(float, u.w << 16);
  f[7] = __builtin_bit_cast(float, u.w & 0xffff0000u);
}
__device__ __forceinline__ uint4 pack8(const float* f) {
  uint4 u;
  u.x = (u32)f2b(f[0]) | ((u32)f2b(f[1]) << 16);
  u.y = (u32)f2b(f[2]) | ((u32)f2b(f[3]) << 16);
  u.z = (u32)f2b(f[4]) | ((u32)f2b(f[5]) << 16);
  u.w = (u32)f2b(f[6]) | ((u32)f2b(f[7]) << 16);
  return u;
}
// decode 8 fp8 (uint2) and add into acc[0..7]
__device__ __forceinline__ void addfp8(uint2 a, float* acc) {
  f32x2 p0 = __builtin_amdgcn_cvt_pk_f32_fp8((int)a.x, false);
  f32x2 p1 = __builtin_amdgcn_cvt_pk_f32_fp8((int)a.x, true);
  f32x2 p2 = __builtin_amdgcn_cvt_pk_f32_fp8((int)a.y, false);
  f32x2 p3 = __builtin_amdgcn_cvt_pk_f32_fp8((int)a.y, true);
  acc[0] += p0.x; acc[1] += p0.y;
  acc[2] += p1.x; acc[3] += p1.y;
  acc[4] += p2.x; acc[5] += p2.y;
  acc[6] += p3.x; acc[7] += p3.y;
}

__device__ __forceinline__ int wave_incl_scan(int x, int lane) {
#pragma unroll
  for (int d = 1; d < 64; d <<= 1) {
    int n = __shfl_up(x, d, 64);
    if (lane >= d) x += n;
  }
  return x;
}

// ================= dispatch 1: prep ∪ bucket (256 thr) =================
__device__ void prep_body(int bid, const float* __restrict__ w1s,
                          const float* __restrict__ w1n,
                          const float* __restrict__ w2s,
                          const float* __restrict__ w2n,
                          const float* __restrict__ wfc, u16* __restrict__ WT1,
                          u16* __restrict__ WT2, u16* __restrict__ WFCT) {
  int i = bid * 256 + threadIdx.x;
  if (i < 32768) {                       // WT1: [256 cols][128 k]
    int c = i >> 7, k = i & 127;
    float v = (c < 128) ? w1s[k * 128 + c] : w1n[k * 128 + (c - 128)];
    WT1[c * 128 + k] = f2b(v);
  } else if (i < 32768 + 65536) {        // WT2: [256 cols][256 k]
    int j = i - 32768;
    int c = j >> 8, k = j & 255;
    float v = (c < 128) ? w2s[k * 128 + c] : w2n[k * 128 + (c - 128)];
    WT2[c * 256 + k] = f2b(v);
  } else {                               // WFCT: [48 cols][256 k], 40..47 zero
    int j = i - 98304;
    int c = j >> 8, k = j & 255;
    float v = (c < 40) ? wfc[k * 40 + c] : 0.f;
    WFCT[c * 256 + k] = f2b(v);
  }
}

__global__ __launch_bounds__(256) void prep_bucket_kernel(
    const float* __restrict__ w1s, const float* __restrict__ w1n,
    const float* __restrict__ w2s, const float* __restrict__ w2n,
    const float* __restrict__ wfc, u16* __restrict__ WT1,
    u16* __restrict__ WT2, u16* __restrict__ WFCT,
    const int* __restrict__ src, const int* __restrict__ dst,
    int* __restrict__ cntg, u32* __restrict__ pairBuf) {
  if (blockIdx.x < PREP_BLKS) {
    prep_body(blockIdx.x, w1s, w1n, w2s, w2n, wfc, WT1, WT2, WFCT);
    return;
  }
  // ---- bucket body ----
  __shared__ unsigned hist[NBUCK];
  __shared__ unsigned gbase[NBUCK];
  __shared__ int sws[4];
  __shared__ u32 stage[CHUNK];     // 16 KB
  __shared__ int tgt[CHUNK];       // 16 KB
  const int tid = threadIdx.x, lane = tid & 63, wid = tid >> 6;
  const int e0 = (blockIdx.x - PREP_BLKS) * CHUNK;

  for (int i = tid; i < NBUCK; i += 256) hist[i] = 0u;
  __syncthreads();

  u32 myW[16];
  int myR[16], myB[16];
#pragma unroll
  for (int k = 0; k < 16; ++k) {
    int e = e0 + k * 256 + tid;
    if (e < N_EDGES) {
      unsigned d = (unsigned)dst[e];
      myW[k] = ((d & 511u) << 17) | (unsigned)src[e];
      myB[k] = (int)(d >> 9);
      myR[k] = (int)atomicAdd(&hist[myB[k]], 1u);
    } else {
      myB[k] = -1;
    }
  }
  __syncthreads();

  int cnt = (tid < NBUCK) ? (int)hist[tid] : 0;
  int inc = wave_incl_scan(cnt, lane);
  if (lane == 63) sws[wid] = inc;
  __syncthreads();
  if (wid == 0) {
    int s = (lane < 4) ? sws[lane] : 0;
    s = wave_incl_scan(s, lane);
    if (lane < 4) sws[lane] = s;
  }
  __syncthreads();
  int excl = (wid ? sws[wid - 1] : 0) + inc - cnt;
  int gofs = 0;
  if (tid < NBUCK && cnt > 0) gofs = tid * BCAP + atomicAdd(&cntg[tid], cnt);
  __syncthreads();
  if (tid < NBUCK) {
    hist[tid] = (unsigned)excl;
    gbase[tid] = (unsigned)gofs;
  }
  __syncthreads();

#pragma unroll
  for (int k = 0; k < 16; ++k) {
    if (myB[k] >= 0) {
      int slot = (int)hist[myB[k]] + myR[k];
      stage[slot] = myW[k];
      tgt[slot] = (int)gbase[myB[k]] + myR[k];
    }
  }
  __syncthreads();
  int nvalid = N_EDGES - e0;
  if (nvalid > CHUNK) nvalid = CHUNK;
  for (int i = tid; i < nvalid; i += 256) pairBuf[tgt[i]] = stage[i];
}

// ================= dispatch 2: csr_build ∪ gemm1 (512 thr, 64KB dyn LDS) =================
__device__ void csr_body(char* smem, int b, const u32* __restrict__ pairBuf,
                         const int* __restrict__ cntg, int* __restrict__ rowptr,
                         int* __restrict__ degA, int* __restrict__ csr) {
  int* lcnt = (int*)smem;            // 512
  int* lofs = lcnt + 512;            // 512
  int* sws = lofs + 512;             // 8
  int* cstage = sws + 8;             // PB_CAP
  const int tid = threadIdx.x;
  const int lane = tid & 63, wid = tid >> 6;
  int nb = cntg[b];
  if (nb > BCAP) nb = BCAP;
  const u32* pp = pairBuf + (size_t)b * BCAP;

  lcnt[tid] = 0;
  __syncthreads();
  for (int i = tid; i < nb; i += 512) atomicAdd(&lcnt[(pp[i] >> 17) & 511], 1);
  __syncthreads();
  int dg = lcnt[tid];
  int pd = (dg + 7) & ~7;            // pad to x8 (2-deep gather)
  int inc = wave_incl_scan(pd, lane);
  if (lane == 63) sws[wid] = inc;
  __syncthreads();
  if (wid == 0) {
    int s = (lane < 8) ? sws[lane] : 0;
    s = wave_incl_scan(s, lane);
    if (lane < 8) sws[lane] = s;
  }
  __syncthreads();
  int excl = (wid ? sws[wid - 1] : 0) + inc - pd;
  int ptot = sws[7];
  int node = b * 512 + tid;
  if (node < N_NODES) {
    rowptr[node] = b * PB_CAP + excl;
    degA[node] = dg;
  }
  lofs[tid] = excl;
  __syncthreads();
  for (int i = tid; i < nb; i += 512) {
    u32 pr = pp[i];
    int pos = atomicAdd(&lofs[(pr >> 17) & 511], 1);
    if (pos < PB_CAP) cstage[pos] = (int)(pr & 0x1FFFFu);
  }
  __syncthreads();
  for (int k = excl + dg; k < excl + pd; ++k)
    if (k < PB_CAP) cstage[k] = N_NODES;  // sentinel pads (zeroed row)
  __syncthreads();
  if (ptot > PB_CAP) ptot = PB_CAP;
  for (int i = tid; i < ptot; i += 512) csr[b * PB_CAP + i] = cstage[i];
}

__device__ void gemm1_body(char* smem, int bid, const float* __restrict__ A,
                           const u16* __restrict__ WT, u16* __restrict__ Cs,
                           u8* __restrict__ Cn8) {
  char* lbc = smem;   // 64 KB: [256 cols][128 k], swizzled RB=256
  const int tid = threadIdx.x;
  for (int i = tid; i < 4096; i += 512) {
    uint4 v = *reinterpret_cast<const uint4*>(WT + i * 8);
    int byte = i * 16;
    int swz = byte ^ (((byte >> 8) & 7) << 4);
    *reinterpret_cast<uint4*>(lbc + swz) = v;
  }

  const int w = tid >> 6, lane = tid & 63;
  const int lrow = lane & 15, lk = lane >> 4;
  const int xr = (lrow & 7) << 4;
  const int rbase = bid * 128 + w * 16;

  bf16x8 af[4];
  {
    int r = rbase + lrow;
    if (r >= N_NODES) r = N_NODES - 1;
    const float* ap = A + (size_t)r * 128 + lk * 8;
#pragma unroll
    for (int ks = 0; ks < 4; ++ks) {
      float4 f0 = *reinterpret_cast<const float4*>(ap + ks * 32);
      float4 f1 = *reinterpret_cast<const float4*>(ap + ks * 32 + 4);
      float f[8] = {f0.x, f0.y, f0.z, f0.w, f1.x, f1.y, f1.z, f1.w};
      af[ks] = __builtin_bit_cast(bf16x8, pack8(f));
    }
  }
  __syncthreads();

  f32x4 acc[16];
#pragma unroll
  for (int ct = 0; ct < 16; ++ct) acc[ct] = f32x4{0.f, 0.f, 0.f, 0.f};
#pragma unroll
  for (int ks = 0; ks < 4; ++ks) {
#pragma unroll
    for (int ct = 0; ct < 16; ++ct) {
      int byte = (ct * 16 + lrow) * 256 + ks * 64 + lk * 16;
      bf16x8 b = __builtin_bit_cast(
          bf16x8, *reinterpret_cast<const uint4*>(lbc + (byte ^ xr)));
      acc[ct] = __builtin_amdgcn_mfma_f32_16x16x32_bf16(af[ks], b, acc[ct], 0, 0, 0);
    }
  }
#pragma unroll
  for (int j = 0; j < 4; ++j) {
    int r = rbase + lk * 4 + j;
    if (r < N_NODES) {
      u16* cs = Cs + (size_t)r * 128 + lrow;
      u8* cn = Cn8 + (size_t)r * 128 + lrow;
#pragma unroll
      for (int ct = 0; ct < 8; ++ct) cs[ct * 16] = f2b(acc[ct][j]);
#pragma unroll
      for (int ct = 0; ct < 8; ++ct) cn[ct * 16] = f2fp8(acc[8 + ct][j]);
    }
  }
}

__global__ __launch_bounds__(512) void csr_gemm1_kernel(
    const u32* __restrict__ pairBuf, const int* __restrict__ cntg,
    int* __restrict__ rowptr, int* __restrict__ degA, int* __restrict__ csr,
    const float* __restrict__ A, const u16* __restrict__ WT,
    u16* __restrict__ Cs, u8* __restrict__ Cn8) {
  extern __shared__ char smem[];
  if (blockIdx.x < NBUCK) {
    csr_body(smem, blockIdx.x, pairBuf, cntg, rowptr, degA, csr);
  } else {
    gemm1_body(smem, blockIdx.x - NBUCK, A, WT, Cs, Cn8);
  }
}

// ================= aggregation helper: fp8 gather, 2-deep =================
__device__ __forceinline__ void agg_node(
    const u16* __restrict__ Xs, const u8* __restrict__ Xn8,
    const int* __restrict__ rowptr, const int* __restrict__ degA,
    const int* __restrict__ csr, const float* __restrict__ bs,
    const float* __restrict__ bn, int node, int g, int lc,
    float* sf, float* nf) {
  int beg = rowptr[node], dg = degA[node];
  int cnt = (dg + 7) & ~7;
  float acc[8] = {0.f, 0.f, 0.f, 0.f, 0.f, 0.f, 0.f, 0.f};
  const u8* colbase = Xn8 + lc * 8;
  const int* cp = csr + beg;
  for (int j = 0; j < cnt; j += 8) {
    int s0 = cp[j + g];
    int s1 = cp[j + 4 + g];
    uint2 a = *reinterpret_cast<const uint2*>(colbase + (size_t)s0 * 128);
    uint2 b = *reinterpret_cast<const uint2*>(colbase + (size_t)s1 * 128);
    addfp8(a, acc);
    addfp8(b, acc);
  }
#pragma unroll
  for (int i = 0; i < 8; ++i) {
    acc[i] += __shfl_xor(acc[i], 32, 64);
    acc[i] += __shfl_xor(acc[i], 16, 64);
  }
  float inv = 1.f / (float)(dg > 0 ? dg : 1);
  uint4 sv4 = *reinterpret_cast<const uint4*>(Xs + (size_t)node * 128 + lc * 8);
  unpack8(sv4, sf);
  float4 b0 = *reinterpret_cast<const float4*>(bs + lc * 8);
  float4 b1 = *reinterpret_cast<const float4*>(bs + lc * 8 + 4);
  float4 c0 = *reinterpret_cast<const float4*>(bn + lc * 8);
  float4 c1 = *reinterpret_cast<const float4*>(bn + lc * 8 + 4);
  float bsv[8] = {b0.x, b0.y, b0.z, b0.w, b1.x, b1.y, b1.z, b1.w};
  float bnv[8] = {c0.x, c0.y, c0.z, c0.w, c1.x, c1.y, c1.z, c1.w};
  float ss = 0.f;
#pragma unroll
  for (int i = 0; i < 8; ++i) {
    sf[i] = fmaxf(sf[i] + bsv[i], 0.f);
    nf[i] = fmaxf(acc[i] * inv + bnv[i], 0.f);
    ss += sf[i] * sf[i] + nf[i] * nf[i];
  }
  ss += __shfl_xor(ss, 1, 64);
  ss += __shfl_xor(ss, 2, 64);
  ss += __shfl_xor(ss, 4, 64);
  ss += __shfl_xor(ss, 8, 64);
  float sc = 1.f / fmaxf(sqrtf(ss), 1e-12f);
#pragma unroll
  for (int i = 0; i < 8; ++i) {
    sf[i] *= sc;
    nf[i] *= sc;
  }
}

// ================= agg: one wave per node, writes H [N,256] =================
__global__ __launch_bounds__(256) void agg_epi_kernel(
    const u16* __restrict__ Xs, const u8* __restrict__ Xn8,
    const int* __restrict__ rowptr, const int* __restrict__ degA,
    const int* __restrict__ csr, const float* __restrict__ bs,
    const float* __restrict__ bn, u16* __restrict__ H) {
  int node = (int)((blockIdx.x * 256 + threadIdx.x) >> 6);
  int lane = threadIdx.x & 63;
  if (node >= N_NODES) return;
  const int g = lane >> 4, lc = lane & 15;
  float sf[8], nf[8];
  agg_node(Xs, Xn8, rowptr, degA, csr, bs, bn, node, g, lc, sf, nf);
  if (g == 0) {
    *reinterpret_cast<uint4*>(H + (size_t)node * 256 + lc * 8) = pack8(sf);
  } else if (g == 1) {
    *reinterpret_cast<uint4*>(H + (size_t)node * 256 + 128 + lc * 8) = pack8(nf);
  }
}

// ================= gemm2: Cs bf16 / Cn fp8, halves staged sequentially =================
__global__ __launch_bounds__(512) void gemm2_kernel(
    const u16* __restrict__ A, const u16* __restrict__ WT,
    u16* __restrict__ Cs, u8* __restrict__ Cn8) {
  __shared__ u16 lb[128 * 256];   // 64 KB: [128 cols][256 k], swizzled RB=512
  char* lbc = reinterpret_cast<char*>(lb);
  const int tid = threadIdx.x;
  const int w = tid >> 6, lane = tid & 63;
  const int lrow = lane & 15, lk = lane >> 4;
  const int xr = (lrow & 7) << 4;
  const int rbase = blockIdx.x * 128 + w * 16;

  bf16x8 af[8];
  {
    int r = rbase + lrow;
    if (r >= N_NODES) r = N_NODES - 1;
    const u16* ap = A + (size_t)r * 256 + lk * 8;
#pragma unroll
    for (int ks = 0; ks < 8; ++ks) af[ks] = ldfrag(ap + ks * 32);
  }

#pragma unroll
  for (int half = 0; half < 2; ++half) {
    const u16* Wsrc = WT + (size_t)half * 128 * 256;
    for (int i = tid; i < 4096; i += 512) {
      uint4 v = *reinterpret_cast<const uint4*>(Wsrc + i * 8);
      int byte = i * 16;
      int swz = byte ^ (((byte >> 9) & 7) << 4);
      *reinterpret_cast<uint4*>(lbc + swz) = v;
    }
    __syncthreads();

    f32x4 acc[8];
#pragma unroll
    for (int ct = 0; ct < 8; ++ct) acc[ct] = f32x4{0.f, 0.f, 0.f, 0.f};
#pragma unroll
    for (int ks = 0; ks < 8; ++ks) {
#pragma unroll
      for (int ct = 0; ct < 8; ++ct) {
        int byte = (ct * 16 + lrow) * 512 + ks * 64 + lk * 16;
        bf16x8 b = __builtin_bit_cast(
            bf16x8, *reinterpret_cast<const uint4*>(lbc + (byte ^ xr)));
        acc[ct] = __builtin_amdgcn_mfma_f32_16x16x32_bf16(af[ks], b, acc[ct], 0, 0, 0);
      }
    }
#pragma unroll
    for (int j = 0; j < 4; ++j) {
      int r = rbase + lk * 4 + j;
      if (r < N_NODES) {
        if (half == 0) {
          u16* cp = Cs + (size_t)r * 128 + lrow;
#pragma unroll
          for (int ct = 0; ct < 8; ++ct) cp[ct * 16] = f2b(acc[ct][j]);
        } else {
          u8* cp = Cn8 + (size_t)r * 128 + lrow;
#pragma unroll
          for (int ct = 0; ct < 8; ++ct) cp[ct * 16] = f2fp8(acc[ct][j]);
        }
      }
    }
    __syncthreads();
  }
}

// ================= FC head: out[N,40] = h2 @ wfc + bfc =================
__global__ __launch_bounds__(256) void fc_kernel(const u16* __restrict__ H2,
                                                 const u16* __restrict__ WFCT,
                                                 const float* __restrict__ bfc,
                                                 float* __restrict__ Out) {
  __shared__ u16 lb[48 * 256];   // 24 KB, swizzled RB=512
  char* lbc = reinterpret_cast<char*>(lb);
  const int tid = threadIdx.x;
#pragma unroll
  for (int i = tid; i < 48 * 256 / 8; i += 256) {
    uint4 v = *reinterpret_cast<const uint4*>(WFCT + i * 8);
    int byte = i * 16;
    int swz = byte ^ (((byte >> 9) & 7) << 4);
    *reinterpret_cast<uint4*>(lbc + swz) = v;
  }
  __syncthreads();
  const int w = tid >> 6, lane = tid & 63;
  const int lrow = lane & 15, lk = lane >> 4;
  const int xr = (lrow & 7) << 4;
  const int rbase = blockIdx.x * 64 + w * 16;

  bf16x8 af[8];
  {
    int r = rbase + lrow;
    if (r >= N_NODES) r = N_NODES - 1;
    const u16* ap = H2 + (size_t)r * 256 + lk * 8;
#pragma unroll
    for (int ks = 0; ks < 8; ++ks) af[ks] = ldfrag(ap + ks * 32);
  }
  f32x4 acc[3];
#pragma unroll
  for (int ct = 0; ct < 3; ++ct) acc[ct] = f32x4{0.f, 0.f, 0.f, 0.f};
#pragma unroll
  for (int ks = 0; ks < 8; ++ks) {
#pragma unroll
    for (int ct = 0; ct < 3; ++ct) {
      int byte = (ct * 16 + lrow) * 512 + ks * 64 + lk * 16;
      bf16x8 b = __builtin_bit_cast(
          bf16x8, *reinterpret_cast<const uint4*>(lbc + (byte ^ xr)));
      acc[ct] = __builtin_amdgcn_mfma_f32_16x16x32_bf16(af[ks], b, acc[ct], 0, 0, 0);
    }
  }
#pragma unroll
  for (int j = 0; j < 4; ++j) {
    int r = rbase + lk * 4 + j;
    if (r < N_NODES) {
#pragma unroll
      for (int ct = 0; ct < 3; ++ct) {
        int col = ct * 16 + lrow;
        if (col < 40) Out[(size_t)r * 40 + col] = acc[ct][j] + bfc[col];
      }
    }
  }
}

// ================= launch =================
extern "C" void kernel_launch(void* const* d_in, const int* in_sizes, int n_in,
                              void* d_out, int out_size, void* d_ws, size_t ws_size,
                              hipStream_t stream) {
  const float* x = (const float*)d_in[0];
  const int* src = (const int*)d_in[1];
  const int* dst = (const int*)d_in[2];
  const float* w1s = (const float*)d_in[3];
  const float* b1s = (const float*)d_in[4];
  const float* w1n = (const float*)d_in[5];
  const float* b1n = (const float*)d_in[6];
  const float* w2s = (const float*)d_in[7];
  const float* b2s = (const float*)d_in[8];
  const float* w2n = (const float*)d_in[9];
  const float* b2n = (const float*)d_in[10];
  const float* wfc = (const float*)d_in[11];
  const float* bfc = (const float*)d_in[12];
  float* out = (float*)d_out;

  char* p = (char*)d_ws;
  auto alloc = [&](size_t bytes) {
    char* r = p;
    p += (bytes + 255) & ~(size_t)255;
    return r;
  };
  u16* XWs = (u16*)alloc((size_t)N_NODES * 128 * 2);        // 25.6 MB
  u8* XWn8 = (u8*)alloc(((size_t)N_NODES + 1) * 128);       // 12.8 MB (+sentinel)
  u16* h1 = (u16*)alloc((size_t)N_NODES * 256 * 2);         // 51.2 MB (h2 aliases)
  u16* WT1 = (u16*)alloc(32768 * 2);
  u16* WT2 = (u16*)alloc(65536 * 2);
  u16* WFCT = (u16*)alloc(12288 * 2);
  u32* pairBuf = (u32*)alloc((size_t)NBUCK * BCAP * 4);     // 9.6 MB
  int* cntg = (int*)alloc(NBUCK * 4);
  int* rowptr = (int*)alloc((size_t)N_NODES * 4);
  int* degA = (int*)alloc((size_t)N_NODES * 4);
  int* csr = (int*)alloc((size_t)NBUCK * PB_CAP * 4);       // 11.2 MB
  u16* h2 = h1;  // gemm2 finishes reading h1 before agg2 writes h2

  hipMemsetAsync(cntg, 0, NBUCK * 4, stream);
  hipMemsetAsync(XWn8 + (size_t)N_NODES * 128, 0, 128, stream);  // sentinel row

  prep_bucket_kernel<<<PREP_BLKS + 391, 256, 0, stream>>>(
      w1s, w1n, w2s, w2n, wfc, WT1, WT2, WFCT, src, dst, cntg, pairBuf);
  csr_gemm1_kernel<<<NBUCK + GEMM1_BLKS, 512, 65536, stream>>>(
      pairBuf, cntg, rowptr, degA, csr, x, WT1, XWs, XWn8);
  agg_epi_kernel<<<25000, 256, 0, stream>>>(XWs, XWn8, rowptr, degA, csr, b1s, b1n, h1);
  gemm2_kernel<<<GEMM1_BLKS, 512, 0, stream>>>(h1, WT2, XWs, XWn8);
  agg_epi_kernel<<<25000, 256, 0, stream>>>(XWs, XWn8, rowptr, degA, csr, b2s, b2n, h2);
  fc_kernel<<<1563, 256, 0, stream>>>(h2, WFCT, bfc, out);
}